// Round 1
// baseline (2001.318 us; speedup 1.0000x reference)
//
#include <hip/hip_runtime.h>
#include <hip/hip_bf16.h>
#include <math.h>

#define Bn 4
#define Tn 1024
#define Cn 1024
#define Hn 16
#define HDn 64
#define FFn 4096

// ---------------------------------------------------------------------------
// LayerNorm: one block (256 threads) per row of C=1024. One float4 per thread.
// ---------------------------------------------------------------------------
__global__ __launch_bounds__(256) void ln_kernel(const float* __restrict__ x,
                                                 const float* __restrict__ g,
                                                 const float* __restrict__ b,
                                                 float* __restrict__ out) {
  int row = blockIdx.x;
  const float4 v = reinterpret_cast<const float4*>(x + (size_t)row * Cn)[threadIdx.x];
  float s  = v.x + v.y + v.z + v.w;
  float s2 = v.x * v.x + v.y * v.y + v.z * v.z + v.w * v.w;
  for (int m = 1; m < 64; m <<= 1) {
    s  += __shfl_xor(s, m, 64);
    s2 += __shfl_xor(s2, m, 64);
  }
  __shared__ float ls[4], ls2[4];
  int wid = threadIdx.x >> 6;
  if ((threadIdx.x & 63) == 0) { ls[wid] = s; ls2[wid] = s2; }
  __syncthreads();
  s  = ls[0] + ls[1] + ls[2] + ls[3];
  s2 = ls2[0] + ls2[1] + ls2[2] + ls2[3];
  const float mean = s * (1.0f / Cn);
  const float var  = s2 * (1.0f / Cn) - mean * mean;
  const float rstd = rsqrtf(var + 1e-5f);
  const float4 gv = reinterpret_cast<const float4*>(g)[threadIdx.x];
  const float4 bv = reinterpret_cast<const float4*>(b)[threadIdx.x];
  float4 o;
  o.x = (v.x - mean) * rstd * gv.x + bv.x;
  o.y = (v.y - mean) * rstd * gv.y + bv.y;
  o.z = (v.z - mean) * rstd * gv.z + bv.z;
  o.w = (v.w - mean) * rstd * gv.w + bv.w;
  reinterpret_cast<float4*>(out + (size_t)row * Cn)[threadIdx.x] = o;
}

// ---------------------------------------------------------------------------
// Repack Wq/Wk/Wv [H,C,HD] into one [C, 3C] matrix (col j: tensor-major,
// then head-major, then d) so QKV becomes a single GEMM.
// ---------------------------------------------------------------------------
__global__ __launch_bounds__(256) void repack_qkv_w(const float* __restrict__ Wq,
                                                    const float* __restrict__ Wk,
                                                    const float* __restrict__ Wv,
                                                    float* __restrict__ W) {
  int idx = blockIdx.x * 256 + threadIdx.x;        // 0 .. 3*C*C-1
  int c  = idx / (3 * Cn);
  int j  = idx % (3 * Cn);
  int ti = j / Cn;
  int jj = j % Cn;
  int h = jj / HDn, d = jj % HDn;
  const float* src = (ti == 0) ? Wq : ((ti == 1) ? Wk : Wv);
  W[idx] = src[((size_t)h * Cn + c) * HDn + d];
}

// ---------------------------------------------------------------------------
// Generic fp32 GEMM with fused epilogue:  C = ep(A[MxK] @ B[KxN] + bias) + res
// 128x128 tile, BK=32, 256 threads, 8x8 micro-tile. act: 0=none, 1=exact GELU.
// ---------------------------------------------------------------------------
__global__ __launch_bounds__(256) void gemm_ep(const float* __restrict__ A,
                                               const float* __restrict__ Bm,
                                               const float* __restrict__ bias,
                                               const float* __restrict__ res,
                                               float* __restrict__ C,
                                               int M, int N, int K, int act) {
  __shared__ float As[32][132];
  __shared__ float Bs[32][132];
  const int tid = threadIdx.x;
  const int tx = tid & 15;          // col group
  const int ty = tid >> 4;          // row group
  const int n0 = blockIdx.x * 128;
  const int m0 = blockIdx.y * 128;

  float acc[8][8];
#pragma unroll
  for (int i = 0; i < 8; ++i)
#pragma unroll
    for (int j = 0; j < 8; ++j) acc[i][j] = 0.0f;

  const int a_kq = tid & 7;         // 8 float4 per 32-wide k row
  const int a_r  = tid >> 3;        // 0..31
  const int b_cq = tid & 31;        // 32 float4 per 128-wide row
  const int b_r  = tid >> 5;        // 0..7

  for (int k0 = 0; k0 < K; k0 += 32) {
#pragma unroll
    for (int p = 0; p < 4; ++p) {
      const int arow = a_r + p * 32;
      const float4 av = *reinterpret_cast<const float4*>(
          &A[(size_t)(m0 + arow) * K + k0 + a_kq * 4]);
      As[a_kq * 4 + 0][arow] = av.x;
      As[a_kq * 4 + 1][arow] = av.y;
      As[a_kq * 4 + 2][arow] = av.z;
      As[a_kq * 4 + 3][arow] = av.w;
      const int brow = b_r + p * 8;
      const float4 bv = *reinterpret_cast<const float4*>(
          &Bm[(size_t)(k0 + brow) * N + n0 + b_cq * 4]);
      *reinterpret_cast<float4*>(&Bs[brow][b_cq * 4]) = bv;
    }
    __syncthreads();
#pragma unroll 8
    for (int kk = 0; kk < 32; ++kk) {
      float a[8], b[8];
      *reinterpret_cast<float4*>(&a[0]) = *reinterpret_cast<float4*>(&As[kk][ty * 4]);
      *reinterpret_cast<float4*>(&a[4]) = *reinterpret_cast<float4*>(&As[kk][64 + ty * 4]);
      *reinterpret_cast<float4*>(&b[0]) = *reinterpret_cast<float4*>(&Bs[kk][tx * 4]);
      *reinterpret_cast<float4*>(&b[4]) = *reinterpret_cast<float4*>(&Bs[kk][64 + tx * 4]);
#pragma unroll
      for (int i = 0; i < 8; ++i)
#pragma unroll
        for (int j = 0; j < 8; ++j) acc[i][j] += a[i] * b[j];
    }
    __syncthreads();
  }

  // epilogue
#pragma unroll
  for (int ih = 0; ih < 2; ++ih)
#pragma unroll
    for (int i = 0; i < 4; ++i) {
      const int row = m0 + ih * 64 + ty * 4 + i;
#pragma unroll
      for (int jh = 0; jh < 2; ++jh) {
        const int col = n0 + jh * 64 + tx * 4;
        float4 v;
        v.x = acc[ih * 4 + i][jh * 4 + 0];
        v.y = acc[ih * 4 + i][jh * 4 + 1];
        v.z = acc[ih * 4 + i][jh * 4 + 2];
        v.w = acc[ih * 4 + i][jh * 4 + 3];
        if (bias) {
          const float4 bb = *reinterpret_cast<const float4*>(&bias[col]);
          v.x += bb.x; v.y += bb.y; v.z += bb.z; v.w += bb.w;
        }
        if (act == 1) {  // exact GELU
          v.x = 0.5f * v.x * (1.0f + erff(v.x * 0.70710678118654752f));
          v.y = 0.5f * v.y * (1.0f + erff(v.y * 0.70710678118654752f));
          v.z = 0.5f * v.z * (1.0f + erff(v.z * 0.70710678118654752f));
          v.w = 0.5f * v.w * (1.0f + erff(v.w * 0.70710678118654752f));
        }
        if (res) {
          const float4 rr = *reinterpret_cast<const float4*>(&res[(size_t)row * N + col]);
          v.x += rr.x; v.y += rr.y; v.z += rr.z; v.w += rr.w;
        }
        *reinterpret_cast<float4*>(&C[(size_t)row * N + col]) = v;
      }
    }
}

// ---------------------------------------------------------------------------
// Flash-style causal attention from packed qkv [B,T,3C] (q|k|v col blocks,
// head-major cols). One block per (qt, h, b): 64 query rows, iterate 64-wide
// key tiles with online softmax. 256 threads = 16x16, 4x4 micro-tiles.
// Output: attn [B,T,C] with heads concatenated.
// ---------------------------------------------------------------------------
__global__ __launch_bounds__(256) void attn_kernel(const float* __restrict__ qkv,
                                                   float* __restrict__ attn) {
  const int qt = blockIdx.x, h = blockIdx.y, b = blockIdx.z;
  const int tid = threadIdx.x;
  const int sq = tid & 15;     // s / d column group (x4)
  const int rq = tid >> 4;     // query-row group (x4)
  const int q0 = qt * 64;

  __shared__ float QsT[64][65];  // [c][r]
  __shared__ float Ks[64][65];   // [s][c]
  __shared__ float Vs[64][65];   // [s][d]
  __shared__ float Ps[64][65];   // [r][s]

  const size_t rowstride = 3 * Cn;
  const size_t base = (size_t)b * Tn * rowstride + (size_t)h * HDn;

  const int lr = tid >> 4, lc = tid & 15;
#pragma unroll
  for (int p = 0; p < 4; ++p) {
    const int row = lr + p * 16;
    const float4 v = *reinterpret_cast<const float4*>(
        qkv + base + (size_t)(q0 + row) * rowstride + lc * 4);
    QsT[lc * 4 + 0][row] = v.x;
    QsT[lc * 4 + 1][row] = v.y;
    QsT[lc * 4 + 2][row] = v.z;
    QsT[lc * 4 + 3][row] = v.w;
  }

  float acc[4][4];
#pragma unroll
  for (int i = 0; i < 4; ++i)
#pragma unroll
    for (int j = 0; j < 4; ++j) acc[i][j] = 0.0f;
  float m_[4] = {-1e30f, -1e30f, -1e30f, -1e30f};
  float l_[4] = {0.0f, 0.0f, 0.0f, 0.0f};

  __syncthreads();

  for (int kt = 0; kt <= qt; ++kt) {
    const int s0 = kt * 64;
    // load K and V tiles
#pragma unroll
    for (int p = 0; p < 4; ++p) {
      const int row = lr + p * 16;
      const float4 kv = *reinterpret_cast<const float4*>(
          qkv + base + Cn + (size_t)(s0 + row) * rowstride + lc * 4);
      Ks[row][lc * 4 + 0] = kv.x;
      Ks[row][lc * 4 + 1] = kv.y;
      Ks[row][lc * 4 + 2] = kv.z;
      Ks[row][lc * 4 + 3] = kv.w;
      const float4 vv = *reinterpret_cast<const float4*>(
          qkv + base + 2 * Cn + (size_t)(s0 + row) * rowstride + lc * 4);
      Vs[row][lc * 4 + 0] = vv.x;
      Vs[row][lc * 4 + 1] = vv.y;
      Vs[row][lc * 4 + 2] = vv.z;
      Vs[row][lc * 4 + 3] = vv.w;
    }
    __syncthreads();

    // S = Q K^T
    float sv[4][4];
#pragma unroll
    for (int i = 0; i < 4; ++i)
#pragma unroll
      for (int j = 0; j < 4; ++j) sv[i][j] = 0.0f;
#pragma unroll 4
    for (int c = 0; c < 64; ++c) {
      float qv[4], kv[4];
#pragma unroll
      for (int i = 0; i < 4; ++i) qv[i] = QsT[c][rq * 4 + i];
#pragma unroll
      for (int ii = 0; ii < 4; ++ii) kv[ii] = Ks[sq * 4 + ii][c];
#pragma unroll
      for (int i = 0; i < 4; ++i)
#pragma unroll
        for (int ii = 0; ii < 4; ++ii) sv[i][ii] += qv[i] * kv[ii];
    }

    const bool diag = (kt == qt);
#pragma unroll
    for (int i = 0; i < 4; ++i) {
      const int t = q0 + rq * 4 + i;
      float mx = -1e30f;
#pragma unroll
      for (int ii = 0; ii < 4; ++ii) {
        float s = sv[i][ii] * 0.125f;
        if (diag && (s0 + sq * 4 + ii) > t) s = -1e30f;
        sv[i][ii] = s;
        mx = fmaxf(mx, s);
      }
      for (int msk = 1; msk < 16; msk <<= 1) mx = fmaxf(mx, __shfl_xor(mx, msk, 64));
      const float mn = fmaxf(m_[i], mx);
      const float sf = __expf(m_[i] - mn);
      m_[i] = mn;
      float psum = 0.0f;
#pragma unroll
      for (int ii = 0; ii < 4; ++ii) {
        const float p = __expf(sv[i][ii] - mn);
        sv[i][ii] = p;
        psum += p;
      }
      for (int msk = 1; msk < 16; msk <<= 1) psum += __shfl_xor(psum, msk, 64);
      l_[i] = l_[i] * sf + psum;
#pragma unroll
      for (int jj = 0; jj < 4; ++jj) acc[i][jj] *= sf;
#pragma unroll
      for (int ii = 0; ii < 4; ++ii) Ps[rq * 4 + i][sq * 4 + ii] = sv[i][ii];
    }
    __syncthreads();

    // acc += P @ V
#pragma unroll 4
    for (int s = 0; s < 64; ++s) {
      float pv[4], vv[4];
#pragma unroll
      for (int i = 0; i < 4; ++i) pv[i] = Ps[rq * 4 + i][s];
#pragma unroll
      for (int jj = 0; jj < 4; ++jj) vv[jj] = Vs[s][sq * 4 + jj];
#pragma unroll
      for (int i = 0; i < 4; ++i)
#pragma unroll
        for (int jj = 0; jj < 4; ++jj) acc[i][jj] += pv[i] * vv[jj];
    }
    __syncthreads();
  }

#pragma unroll
  for (int i = 0; i < 4; ++i) {
    const int t = q0 + rq * 4 + i;
    const float inv = 1.0f / l_[i];
    float4 o;
    o.x = acc[i][0] * inv;
    o.y = acc[i][1] * inv;
    o.z = acc[i][2] * inv;
    o.w = acc[i][3] * inv;
    *reinterpret_cast<float4*>(
        &attn[((size_t)b * Tn + t) * Cn + h * HDn + sq * 4]) = o;
  }
}

// ---------------------------------------------------------------------------
// Launch
// ---------------------------------------------------------------------------
extern "C" void kernel_launch(void* const* d_in, const int* in_sizes, int n_in,
                              void* d_out, int out_size, void* d_ws, size_t ws_size,
                              hipStream_t stream) {
  const float* x      = (const float*)d_in[0];
  const float* ln1_g  = (const float*)d_in[1];
  const float* ln1_b  = (const float*)d_in[2];
  const float* ln2_g  = (const float*)d_in[3];
  const float* ln2_b  = (const float*)d_in[4];
  const float* Wq     = (const float*)d_in[5];
  const float* Wk     = (const float*)d_in[6];
  const float* Wv     = (const float*)d_in[7];
  const float* Wproj  = (const float*)d_in[8];
  const float* bproj  = (const float*)d_in[9];
  const float* W1     = (const float*)d_in[10];
  const float* b1     = (const float*)d_in[11];
  const float* W2     = (const float*)d_in[12];
  const float* b2     = (const float*)d_in[13];
  float* out = (float*)d_out;

  float* ws = (float*)d_ws;
  const size_t M1 = 1024 * 1024;
  float* xn    = ws;                 // 4M floats (xn1, later xn2)
  float* qkv   = ws + 4  * M1;       // 12M floats [4096 x 3072]
  float* attn  = ws + 16 * M1;       // 4M floats  [4096 x 1024]
  float* x2    = ws + 20 * M1;       // 4M floats
  float* wqkv  = ws + 24 * M1;       // 3M floats  [1024 x 3072]
  float* hbuf  = ws + 4  * M1;       // 16M floats [4096 x 4096] (reuses qkv+attn)

  const int Mrows = Bn * Tn;  // 4096

  // 0. repack qkv weights -> [C, 3C]
  repack_qkv_w<<<(3 * Cn * Cn) / 256, 256, 0, stream>>>(Wq, Wk, Wv, wqkv);

  // 1. LN1
  ln_kernel<<<Mrows, 256, 0, stream>>>(x, ln1_g, ln1_b, xn);

  // 2. QKV = xn @ wqkv   [4096 x 3072]
  gemm_ep<<<dim3(3 * Cn / 128, Mrows / 128), 256, 0, stream>>>(
      xn, wqkv, nullptr, nullptr, qkv, Mrows, 3 * Cn, Cn, 0);

  // 3. attention -> attn [4096 x 1024]
  attn_kernel<<<dim3(Tn / 64, Hn, Bn), 256, 0, stream>>>(qkv, attn);

  // 4. x2 = x + attn @ Wproj + bproj
  gemm_ep<<<dim3(Cn / 128, Mrows / 128), 256, 0, stream>>>(
      attn, Wproj, bproj, x, x2, Mrows, Cn, Cn, 0);

  // 5. LN2
  ln_kernel<<<Mrows, 256, 0, stream>>>(x2, ln2_g, ln2_b, xn);

  // 6. h = gelu(xn @ W1 + b1)   [4096 x 4096]
  gemm_ep<<<dim3(FFn / 128, Mrows / 128), 256, 0, stream>>>(
      xn, W1, b1, nullptr, hbuf, Mrows, FFn, Cn, 1);

  // 7. out = x2 + h @ W2 + b2
  gemm_ep<<<dim3(Cn / 128, Mrows / 128), 256, 0, stream>>>(
      hbuf, W2, b2, x2, out, Mrows, Cn, FFn, 0);
}

// Round 2
// 771.123 us; speedup vs baseline: 2.5953x; 2.5953x over previous
//
#include <hip/hip_runtime.h>
#include <hip/hip_bf16.h>
#include <math.h>

#define Bn 4
#define Tn 1024
#define Cn 1024
#define Hn 16
#define HDn 64
#define FFn 4096

typedef unsigned short ushort_t;
typedef __attribute__((ext_vector_type(8))) short bf16x8;
typedef __attribute__((ext_vector_type(4))) float f32x4;

// round-to-nearest-even float -> bf16 bits
__device__ __forceinline__ ushort_t f2bf(float f) {
  unsigned u = __float_as_uint(f);
  u += 0x7fffu + ((u >> 16) & 1u);
  return (ushort_t)(u >> 16);
}

__device__ __forceinline__ void gload_lds16(const void* g, void* l) {
  __builtin_amdgcn_global_load_lds(
      (const __attribute__((address_space(1))) void*)g,
      (__attribute__((address_space(3))) void*)l, 16, 0, 0);
}

// ---------------------------------------------------------------------------
// LayerNorm: one block (256 threads) per row of C=1024 -> bf16 output.
// ---------------------------------------------------------------------------
__global__ __launch_bounds__(256) void ln_kernel(const float* __restrict__ x,
                                                 const float* __restrict__ g,
                                                 const float* __restrict__ b,
                                                 ushort_t* __restrict__ out) {
  int row = blockIdx.x;
  const float4 v = reinterpret_cast<const float4*>(x + (size_t)row * Cn)[threadIdx.x];
  float s  = v.x + v.y + v.z + v.w;
  float s2 = v.x * v.x + v.y * v.y + v.z * v.z + v.w * v.w;
  for (int m = 1; m < 64; m <<= 1) {
    s  += __shfl_xor(s, m, 64);
    s2 += __shfl_xor(s2, m, 64);
  }
  __shared__ float ls[4], ls2[4];
  int wid = threadIdx.x >> 6;
  if ((threadIdx.x & 63) == 0) { ls[wid] = s; ls2[wid] = s2; }
  __syncthreads();
  s  = ls[0] + ls[1] + ls[2] + ls[3];
  s2 = ls2[0] + ls2[1] + ls2[2] + ls2[3];
  const float mean = s * (1.0f / Cn);
  const float var  = s2 * (1.0f / Cn) - mean * mean;
  const float rstd = rsqrtf(var + 1e-5f);
  const float4 gv = reinterpret_cast<const float4*>(g)[threadIdx.x];
  const float4 bv = reinterpret_cast<const float4*>(b)[threadIdx.x];
  float4 o;
  o.x = (v.x - mean) * rstd * gv.x + bv.x;
  o.y = (v.y - mean) * rstd * gv.y + bv.y;
  o.z = (v.z - mean) * rstd * gv.z + bv.z;
  o.w = (v.w - mean) * rstd * gv.w + bv.w;
  uint2 pk;
  pk.x = (unsigned)f2bf(o.x) | ((unsigned)f2bf(o.y) << 16);
  pk.y = (unsigned)f2bf(o.z) | ((unsigned)f2bf(o.w) << 16);
  reinterpret_cast<uint2*>(out + (size_t)row * Cn)[threadIdx.x] = pk;
}

// ---------------------------------------------------------------------------
// Tiled transpose fp32 [K][N] -> bf16 [N][K]  (coalesced both sides)
// grid (N/32, K/32), 256 threads
// ---------------------------------------------------------------------------
__global__ __launch_bounds__(256) void transpose_f2b(const float* __restrict__ in,
                                                     ushort_t* __restrict__ out,
                                                     int K, int N) {
  __shared__ float t[32][33];
  const int n0 = blockIdx.x * 32, k0 = blockIdx.y * 32;
  const int tx = threadIdx.x & 31, ty = threadIdx.x >> 5;
#pragma unroll
  for (int i = 0; i < 4; ++i)
    t[ty + i * 8][tx] = in[(size_t)(k0 + ty + i * 8) * N + n0 + tx];
  __syncthreads();
#pragma unroll
  for (int i = 0; i < 4; ++i)
    out[(size_t)(n0 + ty + i * 8) * K + k0 + tx] = f2bf(t[tx][ty + i * 8]);
}

// Wq/Wk/Wv [H,C,HD] -> bf16 [3C][C] (row n = ti*C + h*64 + d, col c)
// grid (2, 32, 48) : x over d-tiles, y over c-tiles, z = ti*16+h
__global__ __launch_bounds__(256) void repack_qkv_bf(const float* __restrict__ Wq,
                                                     const float* __restrict__ Wk,
                                                     const float* __restrict__ Wv,
                                                     ushort_t* __restrict__ out) {
  __shared__ float t[32][33];
  const int z = blockIdx.z;
  const int ti = z >> 4, h = z & 15;
  const float* in = (ti == 0 ? Wq : (ti == 1 ? Wk : Wv)) + (size_t)h * Cn * HDn; // [C][64]
  ushort_t* o = out + (size_t)(ti * Cn + h * HDn) * Cn;                          // [64][C]
  const int n0 = blockIdx.x * 32, k0 = blockIdx.y * 32;  // n0 over d(64), k0 over c(1024)
  const int tx = threadIdx.x & 31, ty = threadIdx.x >> 5;
#pragma unroll
  for (int i = 0; i < 4; ++i)
    t[ty + i * 8][tx] = in[(size_t)(k0 + ty + i * 8) * HDn + n0 + tx];
  __syncthreads();
#pragma unroll
  for (int i = 0; i < 4; ++i)
    o[(size_t)(n0 + ty + i * 8) * Cn + k0 + tx] = f2bf(t[tx][ty + i * 8]);
}

// ---------------------------------------------------------------------------
// bf16 MFMA GEMM (m97 structure): C = ep(A[MxK] @ Bt[NxK]^T + bias) + res
// 128x128 tile, BK=32, 256 threads (4 waves, each 64x64), global_load_lds x16.
// act: 1 = exact GELU. Output: Cb (bf16) if non-null else Cf (fp32).
// ---------------------------------------------------------------------------
__global__ __launch_bounds__(256) void gemm_bt(const ushort_t* __restrict__ A,
                                               const ushort_t* __restrict__ Bt,
                                               const float* __restrict__ bias,
                                               const float* __restrict__ res,
                                               float* __restrict__ Cf,
                                               ushort_t* __restrict__ Cb,
                                               int M, int N, int K, int act) {
  __shared__ ushort_t As[128 * 32];
  __shared__ ushort_t Bs[128 * 32];
  const int tid = threadIdx.x;
  const int w = tid >> 6, lane = tid & 63;
  const int n0 = blockIdx.x * 128, m0 = blockIdx.y * 128;
  const int wr = w >> 1, wc = w & 1;
  const int lr = lane & 15, lg = lane >> 4;

  f32x4 acc[4][4];
  const f32x4 zero = {0.f, 0.f, 0.f, 0.f};
#pragma unroll
  for (int i = 0; i < 4; ++i)
#pragma unroll
    for (int j = 0; j < 4; ++j) acc[i][j] = zero;

  // staging: wave w stages A rows [w*32, w*32+32) and Bt rows [w*32, w*32+32)
  const int srow = lane >> 2;          // 0..15
  const int skc  = (lane & 3) * 8;     // k element offset (16B chunks)
  const ushort_t* Ag = A  + (size_t)(m0 + w * 32 + srow) * K + skc;
  const ushort_t* Bg = Bt + (size_t)(n0 + w * 32 + srow) * K + skc;
  ushort_t* lA0 = &As[(w * 32) * 32];
  ushort_t* lA1 = &As[(w * 32 + 16) * 32];
  ushort_t* lB0 = &Bs[(w * 32) * 32];
  ushort_t* lB1 = &Bs[(w * 32 + 16) * 32];

  for (int k0 = 0; k0 < K; k0 += 32) {
    gload_lds16(Ag + k0, lA0);
    gload_lds16(Ag + (size_t)16 * K + k0, lA1);
    gload_lds16(Bg + k0, lB0);
    gload_lds16(Bg + (size_t)16 * K + k0, lB1);
    __syncthreads();
    bf16x8 af[4], bf_[4];
#pragma unroll
    for (int m = 0; m < 4; ++m)
      af[m] = *reinterpret_cast<const bf16x8*>(&As[(wr * 64 + m * 16 + lr) * 32 + lg * 8]);
#pragma unroll
    for (int n = 0; n < 4; ++n)
      bf_[n] = *reinterpret_cast<const bf16x8*>(&Bs[(wc * 64 + n * 16 + lr) * 32 + lg * 8]);
#pragma unroll
    for (int m = 0; m < 4; ++m)
#pragma unroll
      for (int n = 0; n < 4; ++n)
        acc[m][n] = __builtin_amdgcn_mfma_f32_16x16x32_bf16(af[m], bf_[n], acc[m][n], 0, 0, 0);
    __syncthreads();
  }

  // epilogue: C/D layout col=lane&15, row=(lane>>4)*4+reg
#pragma unroll
  for (int m = 0; m < 4; ++m) {
    const int rowb = m0 + wr * 64 + m * 16 + lg * 4;
#pragma unroll
    for (int n = 0; n < 4; ++n) {
      const int col = n0 + wc * 64 + n * 16 + lr;
      const float bb = bias ? bias[col] : 0.0f;
      f32x4 v = acc[m][n];
#pragma unroll
      for (int r = 0; r < 4; ++r) {
        float y = v[r] + bb;
        if (act == 1) y = 0.5f * y * (1.0f + erff(y * 0.70710678118654752f));
        if (res) y += res[(size_t)(rowb + r) * N + col];
        if (Cb) Cb[(size_t)(rowb + r) * N + col] = f2bf(y);
        else    Cf[(size_t)(rowb + r) * N + col] = y;
      }
    }
  }
}

// ---------------------------------------------------------------------------
// Flash-style causal attention (fp32 compute) from packed qkv [B,T,3C].
// Output: bf16 attn [B,T,C], heads concatenated.
// ---------------------------------------------------------------------------
__global__ __launch_bounds__(256) void attn_kernel(const float* __restrict__ qkv,
                                                   ushort_t* __restrict__ attn) {
  const int qt = blockIdx.x, h = blockIdx.y, b = blockIdx.z;
  const int tid = threadIdx.x;
  const int sq = tid & 15;
  const int rq = tid >> 4;
  const int q0 = qt * 64;

  __shared__ float QsT[64][65];
  __shared__ float Ks[64][65];
  __shared__ float Vs[64][65];
  __shared__ float Ps[64][65];

  const size_t rowstride = 3 * Cn;
  const size_t base = (size_t)b * Tn * rowstride + (size_t)h * HDn;

  const int lr = tid >> 4, lc = tid & 15;
#pragma unroll
  for (int p = 0; p < 4; ++p) {
    const int row = lr + p * 16;
    const float4 v = *reinterpret_cast<const float4*>(
        qkv + base + (size_t)(q0 + row) * rowstride + lc * 4);
    QsT[lc * 4 + 0][row] = v.x;
    QsT[lc * 4 + 1][row] = v.y;
    QsT[lc * 4 + 2][row] = v.z;
    QsT[lc * 4 + 3][row] = v.w;
  }

  float acc[4][4];
#pragma unroll
  for (int i = 0; i < 4; ++i)
#pragma unroll
    for (int j = 0; j < 4; ++j) acc[i][j] = 0.0f;
  float m_[4] = {-1e30f, -1e30f, -1e30f, -1e30f};
  float l_[4] = {0.0f, 0.0f, 0.0f, 0.0f};

  __syncthreads();

  for (int kt = 0; kt <= qt; ++kt) {
    const int s0 = kt * 64;
#pragma unroll
    for (int p = 0; p < 4; ++p) {
      const int row = lr + p * 16;
      const float4 kv = *reinterpret_cast<const float4*>(
          qkv + base + Cn + (size_t)(s0 + row) * rowstride + lc * 4);
      Ks[row][lc * 4 + 0] = kv.x;
      Ks[row][lc * 4 + 1] = kv.y;
      Ks[row][lc * 4 + 2] = kv.z;
      Ks[row][lc * 4 + 3] = kv.w;
      const float4 vv = *reinterpret_cast<const float4*>(
          qkv + base + 2 * Cn + (size_t)(s0 + row) * rowstride + lc * 4);
      Vs[row][lc * 4 + 0] = vv.x;
      Vs[row][lc * 4 + 1] = vv.y;
      Vs[row][lc * 4 + 2] = vv.z;
      Vs[row][lc * 4 + 3] = vv.w;
    }
    __syncthreads();

    float sv[4][4];
#pragma unroll
    for (int i = 0; i < 4; ++i)
#pragma unroll
      for (int j = 0; j < 4; ++j) sv[i][j] = 0.0f;
#pragma unroll 4
    for (int c = 0; c < 64; ++c) {
      float qv[4], kv[4];
#pragma unroll
      for (int i = 0; i < 4; ++i) qv[i] = QsT[c][rq * 4 + i];
#pragma unroll
      for (int ii = 0; ii < 4; ++ii) kv[ii] = Ks[sq * 4 + ii][c];
#pragma unroll
      for (int i = 0; i < 4; ++i)
#pragma unroll
        for (int ii = 0; ii < 4; ++ii) sv[i][ii] += qv[i] * kv[ii];
    }

    const bool diag = (kt == qt);
#pragma unroll
    for (int i = 0; i < 4; ++i) {
      const int t = q0 + rq * 4 + i;
      float mx = -1e30f;
#pragma unroll
      for (int ii = 0; ii < 4; ++ii) {
        float s = sv[i][ii] * 0.125f;
        if (diag && (s0 + sq * 4 + ii) > t) s = -1e30f;
        sv[i][ii] = s;
        mx = fmaxf(mx, s);
      }
      for (int msk = 1; msk < 16; msk <<= 1) mx = fmaxf(mx, __shfl_xor(mx, msk, 64));
      const float mn = fmaxf(m_[i], mx);
      const float sf = __expf(m_[i] - mn);
      m_[i] = mn;
      float psum = 0.0f;
#pragma unroll
      for (int ii = 0; ii < 4; ++ii) {
        const float p = __expf(sv[i][ii] - mn);
        sv[i][ii] = p;
        psum += p;
      }
      for (int msk = 1; msk < 16; msk <<= 1) psum += __shfl_xor(psum, msk, 64);
      l_[i] = l_[i] * sf + psum;
#pragma unroll
      for (int jj = 0; jj < 4; ++jj) acc[i][jj] *= sf;
#pragma unroll
      for (int ii = 0; ii < 4; ++ii) Ps[rq * 4 + i][sq * 4 + ii] = sv[i][ii];
    }
    __syncthreads();

#pragma unroll 4
    for (int s = 0; s < 64; ++s) {
      float pv[4], vv[4];
#pragma unroll
      for (int i = 0; i < 4; ++i) pv[i] = Ps[rq * 4 + i][s];
#pragma unroll
      for (int jj = 0; jj < 4; ++jj) vv[jj] = Vs[s][sq * 4 + jj];
#pragma unroll
      for (int i = 0; i < 4; ++i)
#pragma unroll
        for (int jj = 0; jj < 4; ++jj) acc[i][jj] += pv[i] * vv[jj];
    }
    __syncthreads();
  }

#pragma unroll
  for (int i = 0; i < 4; ++i) {
    const int t = q0 + rq * 4 + i;
    const float inv = 1.0f / l_[i];
    uint2 pk;
    pk.x = (unsigned)f2bf(acc[i][0] * inv) | ((unsigned)f2bf(acc[i][1] * inv) << 16);
    pk.y = (unsigned)f2bf(acc[i][2] * inv) | ((unsigned)f2bf(acc[i][3] * inv) << 16);
    *reinterpret_cast<uint2*>(
        &attn[((size_t)b * Tn + t) * Cn + h * HDn + sq * 4]) = pk;
  }
}

// ---------------------------------------------------------------------------
// Launch
// ---------------------------------------------------------------------------
extern "C" void kernel_launch(void* const* d_in, const int* in_sizes, int n_in,
                              void* d_out, int out_size, void* d_ws, size_t ws_size,
                              hipStream_t stream) {
  const float* x      = (const float*)d_in[0];
  const float* ln1_g  = (const float*)d_in[1];
  const float* ln1_b  = (const float*)d_in[2];
  const float* ln2_g  = (const float*)d_in[3];
  const float* ln2_b  = (const float*)d_in[4];
  const float* Wq     = (const float*)d_in[5];
  const float* Wk     = (const float*)d_in[6];
  const float* Wv     = (const float*)d_in[7];
  const float* Wproj  = (const float*)d_in[8];
  const float* bproj  = (const float*)d_in[9];
  const float* W1     = (const float*)d_in[10];
  const float* b1     = (const float*)d_in[11];
  const float* W2     = (const float*)d_in[12];
  const float* b2     = (const float*)d_in[13];
  float* out = (float*)d_out;

  char* wsb = (char*)d_ws;
  ushort_t* xn_bf   = (ushort_t*)(wsb);                        // 8MB [4096][1024]
  ushort_t* attn_bf = (ushort_t*)(wsb + ((size_t)8  << 20));   // 8MB [4096][1024]
  float*    x2      = (float*)  (wsb + ((size_t)16 << 20));    // 16MB
  float*    qkv     = (float*)  (wsb + ((size_t)32 << 20));    // 48MB [4096][3072]
  ushort_t* hbuf    = (ushort_t*)(wsb + ((size_t)32 << 20));   // 32MB (reuses qkv)
  ushort_t* wqkv_t  = (ushort_t*)(wsb + ((size_t)80 << 20));   // 6MB [3072][1024]
  ushort_t* wproj_t = (ushort_t*)(wsb + ((size_t)86 << 20));   // 2MB [1024][1024]
  ushort_t* w1_t    = (ushort_t*)(wsb + ((size_t)88 << 20));   // 8MB [4096][1024]
  ushort_t* w2_t    = (ushort_t*)(wsb + ((size_t)96 << 20));   // 8MB [1024][4096]

  const int Mrows = Bn * Tn;  // 4096

  // weight repacks (bf16, [N][K])
  repack_qkv_bf<<<dim3(2, 32, 48), 256, 0, stream>>>(Wq, Wk, Wv, wqkv_t);
  transpose_f2b<<<dim3(Cn / 32, Cn / 32), 256, 0, stream>>>(Wproj, wproj_t, Cn, Cn);
  transpose_f2b<<<dim3(FFn / 32, Cn / 32), 256, 0, stream>>>(W1, w1_t, Cn, FFn);
  transpose_f2b<<<dim3(Cn / 32, FFn / 32), 256, 0, stream>>>(W2, w2_t, FFn, Cn);

  // 1. LN1 -> bf16
  ln_kernel<<<Mrows, 256, 0, stream>>>(x, ln1_g, ln1_b, xn_bf);

  // 2. QKV = xn @ Wqkv -> fp32 [4096 x 3072]
  gemm_bt<<<dim3(3 * Cn / 128, Mrows / 128), 256, 0, stream>>>(
      xn_bf, wqkv_t, nullptr, nullptr, qkv, nullptr, Mrows, 3 * Cn, Cn, 0);

  // 3. attention -> bf16 [4096 x 1024]
  attn_kernel<<<dim3(Tn / 64, Hn, Bn), 256, 0, stream>>>(qkv, attn_bf);

  // 4. x2 = x + attn @ Wproj + bproj  (fp32)
  gemm_bt<<<dim3(Cn / 128, Mrows / 128), 256, 0, stream>>>(
      attn_bf, wproj_t, bproj, x, x2, nullptr, Mrows, Cn, Cn, 0);

  // 5. LN2 -> bf16
  ln_kernel<<<Mrows, 256, 0, stream>>>(x2, ln2_g, ln2_b, xn_bf);

  // 6. h = gelu(xn @ W1 + b1) -> bf16 [4096 x 4096]
  gemm_bt<<<dim3(FFn / 128, Mrows / 128), 256, 0, stream>>>(
      xn_bf, w1_t, b1, nullptr, nullptr, hbuf, Mrows, FFn, Cn, 1);

  // 7. out = x2 + h @ W2 + b2  (fp32)
  gemm_bt<<<dim3(Cn / 128, Mrows / 128), 256, 0, stream>>>(
      hbuf, w2_t, b2, x2, out, nullptr, Mrows, Cn, FFn, 0);
}

// Round 5
// 471.257 us; speedup vs baseline: 4.2468x; 1.6363x over previous
//
#include <hip/hip_runtime.h>
#include <hip/hip_bf16.h>
#include <math.h>

#define Bn 4
#define Tn 1024
#define Cn 1024
#define Hn 16
#define HDn 64
#define FFn 4096

typedef unsigned short ushort_t;
typedef __attribute__((ext_vector_type(8))) short bf16x8;
typedef __attribute__((ext_vector_type(4))) float f32x4;

// round-to-nearest-even float -> bf16 bits
__device__ __forceinline__ ushort_t f2bf(float f) {
  unsigned u = __float_as_uint(f);
  u += 0x7fffu + ((u >> 16) & 1u);
  return (ushort_t)(u >> 16);
}

__device__ __forceinline__ void gload_lds16(const void* g, void* l) {
  __builtin_amdgcn_global_load_lds(
      (const __attribute__((address_space(1))) void*)g,
      (__attribute__((address_space(3))) void*)l, 16, 0, 0);
}

// ---------------------------------------------------------------------------
// LayerNorm: one block (256 threads) per row of C=1024 -> bf16 output.
// ---------------------------------------------------------------------------
__global__ __launch_bounds__(256) void ln_kernel(const float* __restrict__ x,
                                                 const float* __restrict__ g,
                                                 const float* __restrict__ b,
                                                 ushort_t* __restrict__ out) {
  int row = blockIdx.x;
  const float4 v = reinterpret_cast<const float4*>(x + (size_t)row * Cn)[threadIdx.x];
  float s  = v.x + v.y + v.z + v.w;
  float s2 = v.x * v.x + v.y * v.y + v.z * v.z + v.w * v.w;
  for (int m = 1; m < 64; m <<= 1) {
    s  += __shfl_xor(s, m, 64);
    s2 += __shfl_xor(s2, m, 64);
  }
  __shared__ float ls[4], ls2[4];
  int wid = threadIdx.x >> 6;
  if ((threadIdx.x & 63) == 0) { ls[wid] = s; ls2[wid] = s2; }
  __syncthreads();
  s  = ls[0] + ls[1] + ls[2] + ls[3];
  s2 = ls2[0] + ls2[1] + ls2[2] + ls2[3];
  const float mean = s * (1.0f / Cn);
  const float var  = s2 * (1.0f / Cn) - mean * mean;
  const float rstd = rsqrtf(var + 1e-5f);
  const float4 gv = reinterpret_cast<const float4*>(g)[threadIdx.x];
  const float4 bv = reinterpret_cast<const float4*>(b)[threadIdx.x];
  float4 o;
  o.x = (v.x - mean) * rstd * gv.x + bv.x;
  o.y = (v.y - mean) * rstd * gv.y + bv.y;
  o.z = (v.z - mean) * rstd * gv.z + bv.z;
  o.w = (v.w - mean) * rstd * gv.w + bv.w;
  uint2 pk;
  pk.x = (unsigned)f2bf(o.x) | ((unsigned)f2bf(o.y) << 16);
  pk.y = (unsigned)f2bf(o.z) | ((unsigned)f2bf(o.w) << 16);
  reinterpret_cast<uint2*>(out + (size_t)row * Cn)[threadIdx.x] = pk;
}

// ---------------------------------------------------------------------------
// Tiled transpose fp32 [K][N] -> bf16 [N][K]  (coalesced both sides)
// ---------------------------------------------------------------------------
__global__ __launch_bounds__(256) void transpose_f2b(const float* __restrict__ in,
                                                     ushort_t* __restrict__ out,
                                                     int K, int N) {
  __shared__ float t[32][33];
  const int n0 = blockIdx.x * 32, k0 = blockIdx.y * 32;
  const int tx = threadIdx.x & 31, ty = threadIdx.x >> 5;
#pragma unroll
  for (int i = 0; i < 4; ++i)
    t[ty + i * 8][tx] = in[(size_t)(k0 + ty + i * 8) * N + n0 + tx];
  __syncthreads();
#pragma unroll
  for (int i = 0; i < 4; ++i)
    out[(size_t)(n0 + ty + i * 8) * K + k0 + tx] = f2bf(t[tx][ty + i * 8]);
}

// Wq/Wk/Wv [H,C,HD] -> bf16 [3C][C]
__global__ __launch_bounds__(256) void repack_qkv_bf(const float* __restrict__ Wq,
                                                     const float* __restrict__ Wk,
                                                     const float* __restrict__ Wv,
                                                     ushort_t* __restrict__ out) {
  __shared__ float t[32][33];
  const int z = blockIdx.z;
  const int ti = z >> 4, h = z & 15;
  const float* in = (ti == 0 ? Wq : (ti == 1 ? Wk : Wv)) + (size_t)h * Cn * HDn;
  ushort_t* o = out + (size_t)(ti * Cn + h * HDn) * Cn;
  const int n0 = blockIdx.x * 32, k0 = blockIdx.y * 32;
  const int tx = threadIdx.x & 31, ty = threadIdx.x >> 5;
#pragma unroll
  for (int i = 0; i < 4; ++i)
    t[ty + i * 8][tx] = in[(size_t)(k0 + ty + i * 8) * HDn + n0 + tx];
  __syncthreads();
#pragma unroll
  for (int i = 0; i < 4; ++i)
    o[(size_t)(n0 + ty + i * 8) * Cn + k0 + tx] = f2bf(t[tx][ty + i * 8]);
}

// V columns of bf16 qkv [B*T][3C] -> vT [B*H][HD][T]
__global__ __launch_bounds__(256) void vtrans(const ushort_t* __restrict__ qkv,
                                              ushort_t* __restrict__ vT) {
  __shared__ ushort_t t[32][34];
  const int t0 = blockIdx.x * 32;
  const int d0 = blockIdx.y * 32;
  const int bh = blockIdx.z;
  const int b = bh >> 4, h = bh & 15;
  const int tx = threadIdx.x & 31, ty = threadIdx.x >> 5;
#pragma unroll
  for (int i = 0; i < 4; ++i)
    t[ty + i * 8][tx] = qkv[(size_t)(b * Tn + t0 + ty + i * 8) * (3 * Cn) +
                            2 * Cn + h * HDn + d0 + tx];
  __syncthreads();
#pragma unroll
  for (int i = 0; i < 4; ++i)
    vT[(size_t)(bh * HDn + d0 + ty + i * 8) * Tn + t0 + tx] = t[tx][ty + i * 8];
}

// ---------------------------------------------------------------------------
// bf16 MFMA GEMM (m97 structure): C = ep(A[MxK] @ Bt[NxK]^T + bias) + res
// ---------------------------------------------------------------------------
__global__ __launch_bounds__(256) void gemm_bt(const ushort_t* __restrict__ A,
                                               const ushort_t* __restrict__ Bt,
                                               const float* __restrict__ bias,
                                               const float* __restrict__ res,
                                               float* __restrict__ Cf,
                                               ushort_t* __restrict__ Cb,
                                               int M, int N, int K, int act) {
  __shared__ ushort_t As[128 * 32];
  __shared__ ushort_t Bs[128 * 32];
  const int tid = threadIdx.x;
  const int w = tid >> 6, lane = tid & 63;
  const int n0 = blockIdx.x * 128, m0 = blockIdx.y * 128;
  const int wr = w >> 1, wc = w & 1;
  const int lr = lane & 15, lg = lane >> 4;

  f32x4 acc[4][4];
  const f32x4 zero = {0.f, 0.f, 0.f, 0.f};
#pragma unroll
  for (int i = 0; i < 4; ++i)
#pragma unroll
    for (int j = 0; j < 4; ++j) acc[i][j] = zero;

  const int srow = lane >> 2;
  const int skc  = (lane & 3) * 8;
  const ushort_t* Ag = A  + (size_t)(m0 + w * 32 + srow) * K + skc;
  const ushort_t* Bg = Bt + (size_t)(n0 + w * 32 + srow) * K + skc;
  ushort_t* lA0 = &As[(w * 32) * 32];
  ushort_t* lA1 = &As[(w * 32 + 16) * 32];
  ushort_t* lB0 = &Bs[(w * 32) * 32];
  ushort_t* lB1 = &Bs[(w * 32 + 16) * 32];

  for (int k0 = 0; k0 < K; k0 += 32) {
    gload_lds16(Ag + k0, lA0);
    gload_lds16(Ag + (size_t)16 * K + k0, lA1);
    gload_lds16(Bg + k0, lB0);
    gload_lds16(Bg + (size_t)16 * K + k0, lB1);
    __syncthreads();
    bf16x8 af[4], bf_[4];
#pragma unroll
    for (int m = 0; m < 4; ++m)
      af[m] = *reinterpret_cast<const bf16x8*>(&As[(wr * 64 + m * 16 + lr) * 32 + lg * 8]);
#pragma unroll
    for (int n = 0; n < 4; ++n)
      bf_[n] = *reinterpret_cast<const bf16x8*>(&Bs[(wc * 64 + n * 16 + lr) * 32 + lg * 8]);
#pragma unroll
    for (int m = 0; m < 4; ++m)
#pragma unroll
      for (int n = 0; n < 4; ++n)
        acc[m][n] = __builtin_amdgcn_mfma_f32_16x16x32_bf16(af[m], bf_[n], acc[m][n], 0, 0, 0);
    __syncthreads();
  }

#pragma unroll
  for (int m = 0; m < 4; ++m) {
    const int rowb = m0 + wr * 64 + m * 16 + lg * 4;
#pragma unroll
    for (int n = 0; n < 4; ++n) {
      const int col = n0 + wc * 64 + n * 16 + lr;
      const float bb = bias ? bias[col] : 0.0f;
      f32x4 v = acc[m][n];
#pragma unroll
      for (int r = 0; r < 4; ++r) {
        float y = v[r] + bb;
        if (act == 1) y = 0.5f * y * (1.0f + erff(y * 0.70710678118654752f));
        if (res) y += res[(size_t)(rowb + r) * N + col];
        if (Cb) Cb[(size_t)(rowb + r) * N + col] = f2bf(y);
        else    Cf[(size_t)(rowb + r) * N + col] = y;
      }
    }
  }
}

// ---------------------------------------------------------------------------
// MFMA flash attention. Block = (q-tile 64, h, b); 4 waves x 16 q-rows.
// qkv bf16 [B*T][3C]; vT bf16 [B*H][HD][T]; out bf16 [B*T][C].
// LDS tiles [64][64] bf16, XOR-swizzled: elem ^= (row&7)<<3  (bytes: <<4).
// ---------------------------------------------------------------------------
__global__ __launch_bounds__(256) void attn_mfma(const ushort_t* __restrict__ qkv,
                                                 const ushort_t* __restrict__ vT,
                                                 ushort_t* __restrict__ out) {
  const int qt = blockIdx.x, h = blockIdx.y, b = blockIdx.z;
  const int tid = threadIdx.x;
  const int w = tid >> 6;
  const int lane = tid & 63;
  const int lr = lane & 15, lg = lane >> 4;
  const int q0 = qt * 64;
  const int bh = b * Hn + h;

  __shared__ ushort_t Ks[64 * 64];
  __shared__ ushort_t Vts[64 * 64];
  __shared__ ushort_t Ps[64 * 64];

  // Q fragments live in registers (A-operand: lane&15 -> q-row, lane>>4 -> k-group)
  bf16x8 qf[2];
  {
    const ushort_t* qp = qkv + (size_t)(b * Tn + q0 + w * 16 + lr) * (3 * Cn) + h * HDn;
    qf[0] = *reinterpret_cast<const bf16x8*>(qp + lg * 8);
    qf[1] = *reinterpret_cast<const bf16x8*>(qp + 32 + lg * 8);
  }

  f32x4 acc[4];
  const f32x4 fzero = {0.f, 0.f, 0.f, 0.f};
  acc[0] = acc[1] = acc[2] = acc[3] = fzero;
  float m_[4] = {-1e30f, -1e30f, -1e30f, -1e30f};
  float l_[4] = {0.f, 0.f, 0.f, 0.f};

  const int srow = tid >> 3;       // 0..31
  const int sc   = (tid & 7) * 8;  // element offset (16B granule)

  for (int kt = 0; kt <= qt; ++kt) {
    const int s0 = kt * 64;
    // stage K tile [s][d] and Vt tile [d][s] (swizzled)
#pragma unroll
    for (int p = 0; p < 2; ++p) {
      const int row = srow + p * 32;
      const uint4 kv = *reinterpret_cast<const uint4*>(
          qkv + (size_t)(b * Tn + s0 + row) * (3 * Cn) + Cn + h * HDn + sc);
      *reinterpret_cast<uint4*>(&Ks[row * 64 + (sc ^ ((row & 7) << 3))]) = kv;
      const uint4 vv = *reinterpret_cast<const uint4*>(
          vT + (size_t)(bh * HDn + row) * Tn + s0 + sc);
      *reinterpret_cast<uint4*>(&Vts[row * 64 + (sc ^ ((row & 7) << 3))]) = vv;
    }
    __syncthreads();

    // S = Q K^T  (4 col-fragments x 2 k-chunks)
    f32x4 sf[4];
    sf[0] = sf[1] = sf[2] = sf[3] = fzero;
#pragma unroll
    for (int n = 0; n < 4; ++n) {
      const int krow = n * 16 + lr;
#pragma unroll
      for (int c = 0; c < 2; ++c) {
        const bf16x8 kf = *reinterpret_cast<const bf16x8*>(
            &Ks[krow * 64 + ((c * 32 + lg * 8) ^ ((krow & 7) << 3))]);
        sf[n] = __builtin_amdgcn_mfma_f32_16x16x32_bf16(qf[c], kf, sf[n], 0, 0, 0);
      }
    }

    // online softmax (rows q = w*16 + lg*4 + r; cols k = n*16 + lr)
    const bool diag = (kt == qt);
#pragma unroll
    for (int r = 0; r < 4; ++r) {
      const int qg = q0 + w * 16 + lg * 4 + r;
      float mx = -1e30f;
#pragma unroll
      for (int n = 0; n < 4; ++n) {
        float s = sf[n][r] * 0.125f;
        if (diag && (s0 + n * 16 + lr) > qg) s = -1e30f;
        sf[n][r] = s;
        mx = fmaxf(mx, s);
      }
      mx = fmaxf(mx, __shfl_xor(mx, 1));
      mx = fmaxf(mx, __shfl_xor(mx, 2));
      mx = fmaxf(mx, __shfl_xor(mx, 4));
      mx = fmaxf(mx, __shfl_xor(mx, 8));
      const float mn = fmaxf(m_[r], mx);
      const float sfac = __expf(m_[r] - mn);
      m_[r] = mn;
      float ls = 0.f;
#pragma unroll
      for (int n = 0; n < 4; ++n) {
        const float p = __expf(sf[n][r] - mn);
        sf[n][r] = p;
        ls += p;
      }
      ls += __shfl_xor(ls, 1);
      ls += __shfl_xor(ls, 2);
      ls += __shfl_xor(ls, 4);
      ls += __shfl_xor(ls, 8);
      l_[r] = l_[r] * sfac + ls;
#pragma unroll
      for (int n = 0; n < 4; ++n) acc[n][r] *= sfac;
      // P row -> swizzled LDS (wave-private rows)
      const int prow = w * 16 + lg * 4 + r;
#pragma unroll
      for (int n = 0; n < 4; ++n)
        Ps[prow * 64 + ((n * 16 + lr) ^ ((prow & 7) << 3))] = f2bf(sf[n][r]);
    }

    // att += P @ V   (A = P[q][s], B = Vt[d][s])
#pragma unroll
    for (int sb = 0; sb < 2; ++sb) {
      const int prow = w * 16 + lr;
      const bf16x8 pf = *reinterpret_cast<const bf16x8*>(
          &Ps[prow * 64 + ((sb * 32 + lg * 8) ^ ((prow & 7) << 3))]);
#pragma unroll
      for (int nf = 0; nf < 4; ++nf) {
        const int vrow = nf * 16 + lr;
        const bf16x8 vf = *reinterpret_cast<const bf16x8*>(
            &Vts[vrow * 64 + ((sb * 32 + lg * 8) ^ ((vrow & 7) << 3))]);
        acc[nf] = __builtin_amdgcn_mfma_f32_16x16x32_bf16(pf, vf, acc[nf], 0, 0, 0);
      }
    }
    __syncthreads();
  }

  // normalize + write bf16 (heads concatenated)
#pragma unroll
  for (int r = 0; r < 4; ++r) {
    const float inv = 1.0f / l_[r];
    const int qg = q0 + w * 16 + lg * 4 + r;
#pragma unroll
    for (int nf = 0; nf < 4; ++nf)
      out[(size_t)(b * Tn + qg) * Cn + h * HDn + nf * 16 + lr] = f2bf(acc[nf][r] * inv);
  }
}

// ---------------------------------------------------------------------------
// Launch
// ---------------------------------------------------------------------------
extern "C" void kernel_launch(void* const* d_in, const int* in_sizes, int n_in,
                              void* d_out, int out_size, void* d_ws, size_t ws_size,
                              hipStream_t stream) {
  const float* x      = (const float*)d_in[0];
  const float* ln1_g  = (const float*)d_in[1];
  const float* ln1_b  = (const float*)d_in[2];
  const float* ln2_g  = (const float*)d_in[3];
  const float* ln2_b  = (const float*)d_in[4];
  const float* Wq     = (const float*)d_in[5];
  const float* Wk     = (const float*)d_in[6];
  const float* Wv     = (const float*)d_in[7];
  const float* Wproj  = (const float*)d_in[8];
  const float* bproj  = (const float*)d_in[9];
  const float* W1     = (const float*)d_in[10];
  const float* b1     = (const float*)d_in[11];
  const float* W2     = (const float*)d_in[12];
  const float* b2     = (const float*)d_in[13];
  float* out = (float*)d_out;

  char* wsb = (char*)d_ws;
  ushort_t* xn_bf   = (ushort_t*)(wsb);                        // 8MB
  ushort_t* attn_bf = (ushort_t*)(wsb + ((size_t)8  << 20));   // 8MB
  float*    x2      = (float*)  (wsb + ((size_t)16 << 20));    // 16MB
  ushort_t* qkv_bf  = (ushort_t*)(wsb + ((size_t)32 << 20));   // 24MB [4096][3072]
  ushort_t* vTb     = (ushort_t*)(wsb + ((size_t)56 << 20));   // 8MB  [64][64][1024]
  ushort_t* hbuf    = (ushort_t*)(wsb + ((size_t)32 << 20));   // 32MB (reuses qkv+vT)
  ushort_t* wqkv_t  = (ushort_t*)(wsb + ((size_t)64 << 20));   // 6MB
  ushort_t* wproj_t = (ushort_t*)(wsb + ((size_t)70 << 20));   // 2MB
  ushort_t* w1_t    = (ushort_t*)(wsb + ((size_t)72 << 20));   // 8MB
  ushort_t* w2_t    = (ushort_t*)(wsb + ((size_t)80 << 20));   // 8MB

  const int Mrows = Bn * Tn;  // 4096

  // weight repacks (bf16, [N][K])
  repack_qkv_bf<<<dim3(2, 32, 48), 256, 0, stream>>>(Wq, Wk, Wv, wqkv_t);
  transpose_f2b<<<dim3(Cn / 32, Cn / 32), 256, 0, stream>>>(Wproj, wproj_t, Cn, Cn);
  transpose_f2b<<<dim3(FFn / 32, Cn / 32), 256, 0, stream>>>(W1, w1_t, Cn, FFn);
  transpose_f2b<<<dim3(Cn / 32, FFn / 32), 256, 0, stream>>>(W2, w2_t, FFn, Cn);

  // 1. LN1 -> bf16
  ln_kernel<<<Mrows, 256, 0, stream>>>(x, ln1_g, ln1_b, xn_bf);

  // 2. QKV = xn @ Wqkv -> bf16 [4096 x 3072]
  gemm_bt<<<dim3(3 * Cn / 128, Mrows / 128), 256, 0, stream>>>(
      xn_bf, wqkv_t, nullptr, nullptr, nullptr, qkv_bf, Mrows, 3 * Cn, Cn, 0);

  // 2b. V^T for attention
  vtrans<<<dim3(Tn / 32, HDn / 32, Bn * Hn), 256, 0, stream>>>(qkv_bf, vTb);

  // 3. MFMA flash attention -> bf16 [4096 x 1024]
  attn_mfma<<<dim3(Tn / 64, Hn, Bn), 256, 0, stream>>>(qkv_bf, vTb, attn_bf);

  // 4. x2 = x + attn @ Wproj + bproj  (fp32)
  gemm_bt<<<dim3(Cn / 128, Mrows / 128), 256, 0, stream>>>(
      attn_bf, wproj_t, bproj, x, x2, nullptr, Mrows, Cn, Cn, 0);

  // 5. LN2 -> bf16
  ln_kernel<<<Mrows, 256, 0, stream>>>(x2, ln2_g, ln2_b, xn_bf);

  // 6. h = gelu(xn @ W1 + b1) -> bf16 [4096 x 4096]
  gemm_bt<<<dim3(FFn / 128, Mrows / 128), 256, 0, stream>>>(
      xn_bf, w1_t, b1, nullptr, nullptr, hbuf, Mrows, FFn, Cn, 1);

  // 7. out = x2 + h @ W2 + b2  (fp32)
  gemm_bt<<<dim3(Cn / 128, Mrows / 128), 256, 0, stream>>>(
      hbuf, w2_t, b2, x2, out, nullptr, Mrows, Cn, FFn, 0);
}

// Round 6
// 411.444 us; speedup vs baseline: 4.8641x; 1.1454x over previous
//
#include <hip/hip_runtime.h>
#include <hip/hip_bf16.h>
#include <math.h>

#define Bn 4
#define Tn 1024
#define Cn 1024
#define Hn 16
#define HDn 64
#define FFn 4096

typedef unsigned short ushort_t;
typedef __attribute__((ext_vector_type(8))) short bf16x8;
typedef __attribute__((ext_vector_type(4))) float f32x4;

// round-to-nearest-even float -> bf16 bits
__device__ __forceinline__ ushort_t f2bf(float f) {
  unsigned u = __float_as_uint(f);
  u += 0x7fffu + ((u >> 16) & 1u);
  return (ushort_t)(u >> 16);
}

__device__ __forceinline__ void gload_lds16(const void* g, void* l) {
  __builtin_amdgcn_global_load_lds(
      (const __attribute__((address_space(1))) void*)g,
      (__attribute__((address_space(3))) void*)l, 16, 0, 0);
}

// ---------------------------------------------------------------------------
// LayerNorm: one block (256 threads) per row of C=1024 -> bf16 output.
// ---------------------------------------------------------------------------
__global__ __launch_bounds__(256) void ln_kernel(const float* __restrict__ x,
                                                 const float* __restrict__ g,
                                                 const float* __restrict__ b,
                                                 ushort_t* __restrict__ out) {
  int row = blockIdx.x;
  const float4 v = reinterpret_cast<const float4*>(x + (size_t)row * Cn)[threadIdx.x];
  float s  = v.x + v.y + v.z + v.w;
  float s2 = v.x * v.x + v.y * v.y + v.z * v.z + v.w * v.w;
  for (int m = 1; m < 64; m <<= 1) {
    s  += __shfl_xor(s, m, 64);
    s2 += __shfl_xor(s2, m, 64);
  }
  __shared__ float ls[4], ls2[4];
  int wid = threadIdx.x >> 6;
  if ((threadIdx.x & 63) == 0) { ls[wid] = s; ls2[wid] = s2; }
  __syncthreads();
  s  = ls[0] + ls[1] + ls[2] + ls[3];
  s2 = ls2[0] + ls2[1] + ls2[2] + ls2[3];
  const float mean = s * (1.0f / Cn);
  const float var  = s2 * (1.0f / Cn) - mean * mean;
  const float rstd = rsqrtf(var + 1e-5f);
  const float4 gv = reinterpret_cast<const float4*>(g)[threadIdx.x];
  const float4 bv = reinterpret_cast<const float4*>(b)[threadIdx.x];
  float4 o;
  o.x = (v.x - mean) * rstd * gv.x + bv.x;
  o.y = (v.y - mean) * rstd * gv.y + bv.y;
  o.z = (v.z - mean) * rstd * gv.z + bv.z;
  o.w = (v.w - mean) * rstd * gv.w + bv.w;
  uint2 pk;
  pk.x = (unsigned)f2bf(o.x) | ((unsigned)f2bf(o.y) << 16);
  pk.y = (unsigned)f2bf(o.z) | ((unsigned)f2bf(o.w) << 16);
  reinterpret_cast<uint2*>(out + (size_t)row * Cn)[threadIdx.x] = pk;
}

// ---------------------------------------------------------------------------
// Tiled transpose fp32 [K][N] -> bf16 [N][K]  (coalesced both sides)
// ---------------------------------------------------------------------------
__global__ __launch_bounds__(256) void transpose_f2b(const float* __restrict__ in,
                                                     ushort_t* __restrict__ out,
                                                     int K, int N) {
  __shared__ float t[32][33];
  const int n0 = blockIdx.x * 32, k0 = blockIdx.y * 32;
  const int tx = threadIdx.x & 31, ty = threadIdx.x >> 5;
#pragma unroll
  for (int i = 0; i < 4; ++i)
    t[ty + i * 8][tx] = in[(size_t)(k0 + ty + i * 8) * N + n0 + tx];
  __syncthreads();
#pragma unroll
  for (int i = 0; i < 4; ++i)
    out[(size_t)(n0 + ty + i * 8) * K + k0 + tx] = f2bf(t[tx][ty + i * 8]);
}

// Wq/Wk/Wv [H,C,HD] -> bf16 [3C][C]
__global__ __launch_bounds__(256) void repack_qkv_bf(const float* __restrict__ Wq,
                                                     const float* __restrict__ Wk,
                                                     const float* __restrict__ Wv,
                                                     ushort_t* __restrict__ out) {
  __shared__ float t[32][33];
  const int z = blockIdx.z;
  const int ti = z >> 4, h = z & 15;
  const float* in = (ti == 0 ? Wq : (ti == 1 ? Wk : Wv)) + (size_t)h * Cn * HDn;
  ushort_t* o = out + (size_t)(ti * Cn + h * HDn) * Cn;
  const int n0 = blockIdx.x * 32, k0 = blockIdx.y * 32;
  const int tx = threadIdx.x & 31, ty = threadIdx.x >> 5;
#pragma unroll
  for (int i = 0; i < 4; ++i)
    t[ty + i * 8][tx] = in[(size_t)(k0 + ty + i * 8) * HDn + n0 + tx];
  __syncthreads();
#pragma unroll
  for (int i = 0; i < 4; ++i)
    o[(size_t)(n0 + ty + i * 8) * Cn + k0 + tx] = f2bf(t[tx][ty + i * 8]);
}

// V columns of bf16 qkv [B*T][3C] -> vT [B*H][HD][T]
__global__ __launch_bounds__(256) void vtrans(const ushort_t* __restrict__ qkv,
                                              ushort_t* __restrict__ vT) {
  __shared__ ushort_t t[32][34];
  const int t0 = blockIdx.x * 32;
  const int d0 = blockIdx.y * 32;
  const int bh = blockIdx.z;
  const int b = bh >> 4, h = bh & 15;
  const int tx = threadIdx.x & 31, ty = threadIdx.x >> 5;
#pragma unroll
  for (int i = 0; i < 4; ++i)
    t[ty + i * 8][tx] = qkv[(size_t)(b * Tn + t0 + ty + i * 8) * (3 * Cn) +
                            2 * Cn + h * HDn + d0 + tx];
  __syncthreads();
#pragma unroll
  for (int i = 0; i < 4; ++i)
    vT[(size_t)(bh * HDn + d0 + ty + i * 8) * Tn + t0 + tx] = t[tx][ty + i * 8];
}

// ---------------------------------------------------------------------------
// bf16 MFMA GEMM, prefetch-pipelined (T3 minimum recipe):
//   C = ep(A[MxK] @ Bt[NxK]^T + bias) + res
// BN=128 fixed. BM=128: 4 waves 2x2 (64x64 each). BM=64: 4 waves 1x4
// (64x32 each) for skinny-N GEMMs -> 2 blocks/CU. Double-buffered LDS;
// stage(next) before compute(cur); ONE barrier per K-step.
// ---------------------------------------------------------------------------
template <int BM>
__global__ __launch_bounds__(256) void gemm_bt(const ushort_t* __restrict__ A,
                                               const ushort_t* __restrict__ Bt,
                                               const float* __restrict__ bias,
                                               const float* __restrict__ res,
                                               float* __restrict__ Cf,
                                               ushort_t* __restrict__ Cb,
                                               int M, int N, int K, int act) {
  constexpr int FN = (BM == 128) ? 4 : 2;
  __shared__ ushort_t As[2][BM * 32];
  __shared__ ushort_t Bs[2][128 * 32];
  const int tid = threadIdx.x;
  const int w = tid >> 6, lane = tid & 63;
  const int n0 = blockIdx.x * 128, m0 = blockIdx.y * BM;
  const int woffM = (BM == 128) ? (w >> 1) * 64 : 0;
  const int woffN = (BM == 128) ? (w & 1) * 64 : w * 32;
  const int lr = lane & 15, lg = lane >> 4;

  f32x4 acc[4][FN];
  const f32x4 zero = {0.f, 0.f, 0.f, 0.f};
#pragma unroll
  for (int i = 0; i < 4; ++i)
#pragma unroll
    for (int j = 0; j < FN; ++j) acc[i][j] = zero;

  const int srow = lane >> 2;          // 0..15
  const int skc  = (lane & 3) * 8;     // k element offset
  const int arow0 = (BM == 128) ? (w * 32) : (w * 16);
  const ushort_t* Ag = A  + (size_t)(m0 + arow0 + srow) * K + skc;
  const ushort_t* Bg = Bt + (size_t)(n0 + w * 32 + srow) * K + skc;

  const int NT = K >> 5;

  auto stage = [&](int buf, int k0) {
    gload_lds16(Ag + k0, &As[buf][arow0 * 32]);
    if (BM == 128)
      gload_lds16(Ag + (size_t)16 * K + k0, &As[buf][(arow0 + 16) * 32]);
    gload_lds16(Bg + k0, &Bs[buf][(w * 32) * 32]);
    gload_lds16(Bg + (size_t)16 * K + k0, &Bs[buf][(w * 32 + 16) * 32]);
  };

  stage(0, 0);
  __syncthreads();   // implicit vmcnt(0): tile 0 resident

  int cur = 0;
  for (int t = 0; t < NT; ++t) {
    if (t + 1 < NT) stage(cur ^ 1, (t + 1) << 5);   // prefetch next tile
    bf16x8 af[4], bfr[FN];
#pragma unroll
    for (int m = 0; m < 4; ++m)
      af[m] = *reinterpret_cast<const bf16x8*>(
          &As[cur][(woffM + m * 16 + lr) * 32 + lg * 8]);
#pragma unroll
    for (int n = 0; n < FN; ++n)
      bfr[n] = *reinterpret_cast<const bf16x8*>(
          &Bs[cur][(woffN + n * 16 + lr) * 32 + lg * 8]);
#pragma unroll
    for (int m = 0; m < 4; ++m)
#pragma unroll
      for (int n = 0; n < FN; ++n)
        acc[m][n] = __builtin_amdgcn_mfma_f32_16x16x32_bf16(af[m], bfr[n], acc[m][n], 0, 0, 0);
    __syncthreads();   // implicit vmcnt(0): prefetch complete; safe to swap
    cur ^= 1;
  }

  // epilogue: C/D layout col=lane&15, row=(lane>>4)*4+reg
#pragma unroll
  for (int m = 0; m < 4; ++m) {
    const int rowb = m0 + woffM + m * 16 + lg * 4;
#pragma unroll
    for (int n = 0; n < FN; ++n) {
      const int col = n0 + woffN + n * 16 + lr;
      const float bb = bias ? bias[col] : 0.0f;
      f32x4 v = acc[m][n];
#pragma unroll
      for (int r = 0; r < 4; ++r) {
        float y = v[r] + bb;
        if (act == 1) y = 0.5f * y * (1.0f + erff(y * 0.70710678118654752f));
        if (res) y += res[(size_t)(rowb + r) * N + col];
        if (Cb) Cb[(size_t)(rowb + r) * N + col] = f2bf(y);
        else    Cf[(size_t)(rowb + r) * N + col] = y;
      }
    }
  }
}

// ---------------------------------------------------------------------------
// MFMA flash attention. Block = (q-tile 64, h, b); 4 waves x 16 q-rows.
// qkv bf16 [B*T][3C]; vT bf16 [B*H][HD][T]; out bf16 [B*T][C].
// LDS tiles [64][64] bf16, XOR-swizzled: elem ^= (row&7)<<3.
// ---------------------------------------------------------------------------
__global__ __launch_bounds__(256) void attn_mfma(const ushort_t* __restrict__ qkv,
                                                 const ushort_t* __restrict__ vT,
                                                 ushort_t* __restrict__ out) {
  const int qt = blockIdx.x, h = blockIdx.y, b = blockIdx.z;
  const int tid = threadIdx.x;
  const int w = tid >> 6;
  const int lane = tid & 63;
  const int lr = lane & 15, lg = lane >> 4;
  const int q0 = qt * 64;
  const int bh = b * Hn + h;

  __shared__ ushort_t Ks[64 * 64];
  __shared__ ushort_t Vts[64 * 64];
  __shared__ ushort_t Ps[64 * 64];

  bf16x8 qf[2];
  {
    const ushort_t* qp = qkv + (size_t)(b * Tn + q0 + w * 16 + lr) * (3 * Cn) + h * HDn;
    qf[0] = *reinterpret_cast<const bf16x8*>(qp + lg * 8);
    qf[1] = *reinterpret_cast<const bf16x8*>(qp + 32 + lg * 8);
  }

  f32x4 acc[4];
  const f32x4 fzero = {0.f, 0.f, 0.f, 0.f};
  acc[0] = acc[1] = acc[2] = acc[3] = fzero;
  float m_[4] = {-1e30f, -1e30f, -1e30f, -1e30f};
  float l_[4] = {0.f, 0.f, 0.f, 0.f};

  const int srow = tid >> 3;       // 0..31
  const int sc   = (tid & 7) * 8;  // element offset (16B granule)

  for (int kt = 0; kt <= qt; ++kt) {
    const int s0 = kt * 64;
#pragma unroll
    for (int p = 0; p < 2; ++p) {
      const int row = srow + p * 32;
      const uint4 kv = *reinterpret_cast<const uint4*>(
          qkv + (size_t)(b * Tn + s0 + row) * (3 * Cn) + Cn + h * HDn + sc);
      *reinterpret_cast<uint4*>(&Ks[row * 64 + (sc ^ ((row & 7) << 3))]) = kv;
      const uint4 vv = *reinterpret_cast<const uint4*>(
          vT + (size_t)(bh * HDn + row) * Tn + s0 + sc);
      *reinterpret_cast<uint4*>(&Vts[row * 64 + (sc ^ ((row & 7) << 3))]) = vv;
    }
    __syncthreads();

    f32x4 sf[4];
    sf[0] = sf[1] = sf[2] = sf[3] = fzero;
#pragma unroll
    for (int n = 0; n < 4; ++n) {
      const int krow = n * 16 + lr;
#pragma unroll
      for (int c = 0; c < 2; ++c) {
        const bf16x8 kf = *reinterpret_cast<const bf16x8*>(
            &Ks[krow * 64 + ((c * 32 + lg * 8) ^ ((krow & 7) << 3))]);
        sf[n] = __builtin_amdgcn_mfma_f32_16x16x32_bf16(qf[c], kf, sf[n], 0, 0, 0);
      }
    }

    const bool diag = (kt == qt);
#pragma unroll
    for (int r = 0; r < 4; ++r) {
      const int qg = q0 + w * 16 + lg * 4 + r;
      float mx = -1e30f;
#pragma unroll
      for (int n = 0; n < 4; ++n) {
        float s = sf[n][r] * 0.125f;
        if (diag && (s0 + n * 16 + lr) > qg) s = -1e30f;
        sf[n][r] = s;
        mx = fmaxf(mx, s);
      }
      mx = fmaxf(mx, __shfl_xor(mx, 1));
      mx = fmaxf(mx, __shfl_xor(mx, 2));
      mx = fmaxf(mx, __shfl_xor(mx, 4));
      mx = fmaxf(mx, __shfl_xor(mx, 8));
      const float mn = fmaxf(m_[r], mx);
      const float sfac = __expf(m_[r] - mn);
      m_[r] = mn;
      float ls = 0.f;
#pragma unroll
      for (int n = 0; n < 4; ++n) {
        const float p = __expf(sf[n][r] - mn);
        sf[n][r] = p;
        ls += p;
      }
      ls += __shfl_xor(ls, 1);
      ls += __shfl_xor(ls, 2);
      ls += __shfl_xor(ls, 4);
      ls += __shfl_xor(ls, 8);
      l_[r] = l_[r] * sfac + ls;
#pragma unroll
      for (int n = 0; n < 4; ++n) acc[n][r] *= sfac;
      const int prow = w * 16 + lg * 4 + r;
#pragma unroll
      for (int n = 0; n < 4; ++n)
        Ps[prow * 64 + ((n * 16 + lr) ^ ((prow & 7) << 3))] = f2bf(sf[n][r]);
    }

#pragma unroll
    for (int sb = 0; sb < 2; ++sb) {
      const int prow = w * 16 + lr;
      const bf16x8 pf = *reinterpret_cast<const bf16x8*>(
          &Ps[prow * 64 + ((sb * 32 + lg * 8) ^ ((prow & 7) << 3))]);
#pragma unroll
      for (int nf = 0; nf < 4; ++nf) {
        const int vrow = nf * 16 + lr;
        const bf16x8 vf = *reinterpret_cast<const bf16x8*>(
            &Vts[vrow * 64 + ((sb * 32 + lg * 8) ^ ((vrow & 7) << 3))]);
        acc[nf] = __builtin_amdgcn_mfma_f32_16x16x32_bf16(pf, vf, acc[nf], 0, 0, 0);
      }
    }
    __syncthreads();
  }

#pragma unroll
  for (int r = 0; r < 4; ++r) {
    const float inv = 1.0f / l_[r];
    const int qg = q0 + w * 16 + lg * 4 + r;
#pragma unroll
    for (int nf = 0; nf < 4; ++nf)
      out[(size_t)(b * Tn + qg) * Cn + h * HDn + nf * 16 + lr] = f2bf(acc[nf][r] * inv);
  }
}

// ---------------------------------------------------------------------------
// Launch
// ---------------------------------------------------------------------------
extern "C" void kernel_launch(void* const* d_in, const int* in_sizes, int n_in,
                              void* d_out, int out_size, void* d_ws, size_t ws_size,
                              hipStream_t stream) {
  const float* x      = (const float*)d_in[0];
  const float* ln1_g  = (const float*)d_in[1];
  const float* ln1_b  = (const float*)d_in[2];
  const float* ln2_g  = (const float*)d_in[3];
  const float* ln2_b  = (const float*)d_in[4];
  const float* Wq     = (const float*)d_in[5];
  const float* Wk     = (const float*)d_in[6];
  const float* Wv     = (const float*)d_in[7];
  const float* Wproj  = (const float*)d_in[8];
  const float* bproj  = (const float*)d_in[9];
  const float* W1     = (const float*)d_in[10];
  const float* b1     = (const float*)d_in[11];
  const float* W2     = (const float*)d_in[12];
  const float* b2     = (const float*)d_in[13];
  float* out = (float*)d_out;

  char* wsb = (char*)d_ws;
  ushort_t* xn_bf   = (ushort_t*)(wsb);                        // 8MB
  ushort_t* attn_bf = (ushort_t*)(wsb + ((size_t)8  << 20));   // 8MB
  float*    x2      = (float*)  (wsb + ((size_t)16 << 20));    // 16MB
  ushort_t* qkv_bf  = (ushort_t*)(wsb + ((size_t)32 << 20));   // 24MB [4096][3072]
  ushort_t* vTb     = (ushort_t*)(wsb + ((size_t)56 << 20));   // 8MB  [64][64][1024]
  ushort_t* hbuf    = (ushort_t*)(wsb + ((size_t)32 << 20));   // 32MB (reuses qkv+vT)
  ushort_t* wqkv_t  = (ushort_t*)(wsb + ((size_t)64 << 20));   // 6MB
  ushort_t* wproj_t = (ushort_t*)(wsb + ((size_t)70 << 20));   // 2MB
  ushort_t* w1_t    = (ushort_t*)(wsb + ((size_t)72 << 20));   // 8MB
  ushort_t* w2_t    = (ushort_t*)(wsb + ((size_t)80 << 20));   // 8MB

  const int Mrows = Bn * Tn;  // 4096

  // weight repacks (bf16, [N][K])
  repack_qkv_bf<<<dim3(2, 32, 48), 256, 0, stream>>>(Wq, Wk, Wv, wqkv_t);
  transpose_f2b<<<dim3(Cn / 32, Cn / 32), 256, 0, stream>>>(Wproj, wproj_t, Cn, Cn);
  transpose_f2b<<<dim3(FFn / 32, Cn / 32), 256, 0, stream>>>(W1, w1_t, Cn, FFn);
  transpose_f2b<<<dim3(Cn / 32, FFn / 32), 256, 0, stream>>>(W2, w2_t, FFn, Cn);

  // 1. LN1 -> bf16
  ln_kernel<<<Mrows, 256, 0, stream>>>(x, ln1_g, ln1_b, xn_bf);

  // 2. QKV = xn @ Wqkv -> bf16 [4096 x 3072]   (768 blocks, 3/CU)
  gemm_bt<128><<<dim3(3 * Cn / 128, Mrows / 128), 256, 0, stream>>>(
      xn_bf, wqkv_t, nullptr, nullptr, nullptr, qkv_bf, Mrows, 3 * Cn, Cn, 0);

  // 2b. V^T for attention
  vtrans<<<dim3(Tn / 32, HDn / 32, Bn * Hn), 256, 0, stream>>>(qkv_bf, vTb);

  // 3. MFMA flash attention -> bf16 [4096 x 1024]
  attn_mfma<<<dim3(Tn / 64, Hn, Bn), 256, 0, stream>>>(qkv_bf, vTb, attn_bf);

  // 4. x2 = x + attn @ Wproj + bproj  (fp32)   (BM=64: 512 blocks, 2/CU)
  gemm_bt<64><<<dim3(Cn / 128, Mrows / 64), 256, 0, stream>>>(
      attn_bf, wproj_t, bproj, x, x2, nullptr, Mrows, Cn, Cn, 0);

  // 5. LN2 -> bf16
  ln_kernel<<<Mrows, 256, 0, stream>>>(x2, ln2_g, ln2_b, xn_bf);

  // 6. h = gelu(xn @ W1 + b1) -> bf16 [4096 x 4096]   (1024 blocks, 4/CU)
  gemm_bt<128><<<dim3(FFn / 128, Mrows / 128), 256, 0, stream>>>(
      xn_bf, w1_t, b1, nullptr, nullptr, hbuf, Mrows, FFn, Cn, 1);

  // 7. out = x2 + h @ W2 + b2  (fp32)   (BM=64: 512 blocks, 2/CU)
  gemm_bt<64><<<dim3(Cn / 128, Mrows / 64), 256, 0, stream>>>(
      hbuf, w2_t, b2, x2, out, nullptr, Mrows, Cn, FFn, 0);
}